// Round 2
// baseline (203.341 us; speedup 1.0000x reference)
//
#include <hip/hip_runtime.h>
#include <hip/hip_bf16.h>
#include <math.h>

#define BB 64
#define QQ 900
#define GG 100
#define NCLS 10
#define CP1 11

#define STRIDE 960   // 64*15: every lane owns exactly KPL columns; cols 900..959 are +inf pads
#define KPL 15
#define NT 512
#define NW 8
#define QMASK 255    // ring queue; live entries <= n <= 100 < 256
#define ROUND_CAP 20000

#define NCH 8        // q-chunks in cost phase
#define QCH 128      // queries per chunk

#define CLS_W 2.0f
#define L1_W 5.0f
#define GIOU_W 2.0f

struct Accum {
  double wnll, wt, l1, gl;
  int nm, counter;
  int pad[6];
};

// ---------------- fully fused: per-batch cost + JV + loss in one block ----------------
// 64 blocks x 512 threads, one batch per block. Cost phase writes this batch's
// cost slice to global (read back by the same block: L1/L2-coherent after
// threadfence_block+barrier) and keeps per-row (m1,m2,argmin) in registers.
// All fp op orders identical to the verified split version -> bit-identical loss.
__global__ __launch_bounds__(NT) void fused_kernel(
    const float* __restrict__ logits, const float* __restrict__ pboxes,
    const int* __restrict__ gcls, const float* __restrict__ gboxes,
    float* __restrict__ cost, Accum* acc, float* out) {
  const int b = blockIdx.x;
  const int tid = threadIdx.x;
  const int lane = tid & 63;
  const int w = tid >> 6;
  const int ql = tid & (QCH - 1);
  const int gq = tid >> 7;                 // 0..3: interleaved g-quarter (g = gq + 4i)

  __shared__ float s_gb[GG * 4];
  __shared__ int   s_gc[GG];
  __shared__ float s_prob[QCH * 13];       // per-chunk probs
  __shared__ float s_c[GG][QCH + 1];       // chunk transpose; +1 pad -> conflict-free
  __shared__ float s_mx[QQ], s_lse[QQ];    // softmax stats for Phase E
  __shared__ float vl[STRIDE + 2];         // column duals (f32), <= 0
  __shared__ int   p[QQ + 1];              // column -> owning row (1-based), 0 = free
  __shared__ unsigned long long way64[STRIDE + 2];  // regret-max claim keys
  __shared__ int   queue[QMASK + 1];
  __shared__ int   sh_n, sh_qtail;
  __shared__ double r0[NW], r1[NW], r2[NW], r3[NW];
  __shared__ int r4[NW];

  if (tid == 0) { sh_n = 0; sh_qtail = 0; }
  for (int j = tid; j <= QQ; j += NT) p[j] = 0;
  for (int j = tid; j < STRIDE + 2; j += NT) { vl[j] = 0.f; way64[j] = 0ull; }
  for (int i = tid; i < GG * 4; i += NT) s_gb[i] = gboxes[b * GG * 4 + i];
  if (tid < GG) s_gc[tid] = gcls[b * GG + tid];
  __syncthreads();
  if (tid < GG && s_gc[tid] >= 0) atomicAdd(&sh_n, 1);
  __syncthreads();
  const int n = sh_n;
  float* Cb = cost + (size_t)b * GG * STRIDE;

  // ---- Phase A: cost matrix (8 chunks) + running per-row (m1,m2,argmin) in registers ----
  float rm1 = 3e38f, rm2 = 3e38f;
  int rj1 = 0x7FFFFFFF;
  for (int ch = 0; ch < NCH; ++ch) {
    const int qbase = ch * QCH;
    if (tid < QCH) {                       // softmax once per q (same op order as before)
      const int q = qbase + tid;
      if (q < QQ) {
        const float* lg = logits + ((size_t)b * QQ + q) * CP1;
        float l[CP1];
        float mx = -1e30f;
        for (int c = 0; c < CP1; ++c) { l[c] = lg[c]; mx = fmaxf(mx, l[c]); }
        float se = 0.f;
        for (int c = 0; c < CP1; ++c) { l[c] = expf(l[c] - mx); se += l[c]; }
        const float inv = 1.0f / se;
        for (int c = 0; c < NCLS; ++c) s_prob[tid * 13 + c] = l[c] * inv;
        s_mx[q] = mx;
        s_lse[q] = logf(se);
      }
    }
    __syncthreads();

    const int q = qbase + ql;
    float pcx = 0.f, pcy = 0.f, pw = 0.f, ph = 0.f;
    if (q < QQ) {
      const float* pb = pboxes + ((size_t)b * QQ + q) * 4;
      pcx = pb[0]; pcy = pb[1]; pw = pb[2]; ph = pb[3];
    }
    const float px1 = pcx - 0.5f * pw, py1 = pcy - 0.5f * ph;
    const float px2 = pcx + 0.5f * pw, py2 = pcy + 0.5f * ph;
    const float pa = fmaxf(px2 - px1, 0.f) * fmaxf(py2 - py1, 0.f);
    float* crow = Cb + q;
    for (int g = gq; g < n; g += 4) {      // interleave: balanced for any n
      float cv = 3e38f;
      if (q < QQ) {
        int cls = s_gc[g];
        cls = cls < 0 ? 0 : (cls > NCLS - 1 ? NCLS - 1 : cls);
        const float cc = -s_prob[ql * 13 + cls];
        const float gcx = s_gb[g * 4 + 0], gcy = s_gb[g * 4 + 1];
        const float gw  = s_gb[g * 4 + 2], gh2 = s_gb[g * 4 + 3];
        const float l1 = fabsf(pcx - gcx) + fabsf(pcy - gcy) + fabsf(pw - gw) + fabsf(ph - gh2);
        const float gx1 = gcx - 0.5f * gw, gy1 = gcy - 0.5f * gh2;
        const float gx2 = gcx + 0.5f * gw, gy2 = gcy + 0.5f * gh2;
        const float ga = fmaxf(gx2 - gx1, 0.f) * fmaxf(gy2 - gy1, 0.f);
        const float ltx = fmaxf(px1, gx1), lty = fmaxf(py1, gy1);
        const float rbx = fminf(px2, gx2), rby = fminf(py2, gy2);
        const float iw = fmaxf(rbx - ltx, 0.f), ih = fmaxf(rby - lty, 0.f);
        const float inter = iw * ih;
        const float uni = pa + ga - inter;
        const float iou = inter / fmaxf(uni, 1e-6f);
        const float ex1 = fminf(px1, gx1), ey1 = fminf(py1, gy1);
        const float ex2 = fmaxf(px2, gx2), ey2 = fmaxf(py2, gy2);
        const float ew = fmaxf(ex2 - ex1, 0.f), eh = fmaxf(ey2 - ey1, 0.f);
        const float enc = ew * eh;
        const float giou = iou - (enc - uni) / fmaxf(enc, 1e-6f);
        cv = CLS_W * cc + L1_W * l1 - GIOU_W * giou;
        crow[(size_t)g * STRIDE] = cv;
      } else if (q < STRIDE) {
        crow[(size_t)g * STRIDE] = 1e30f;  // pad columns: Phase D scans them
      }
      s_c[g][ql] = cv;                     // 3e38 beyond QQ: excluded from mins
    }
    __syncthreads();

    // per-row chunk mins: thread t = row, serial scan, 2 ILP chains (same order as split ver)
    if (tid < n) {
      const int kmax = (ch == NCH - 1) ? (QQ - (NCH - 1) * QCH) : QCH;  // 4 or 128
      float m1 = 3e38f, m2 = 3e38f, n1 = 3e38f, n2 = 3e38f;
      int j1 = 0x7FFFFFFF, i1 = 0x7FFFFFFF;
      const int ka = kmax < 64 ? kmax : 64;
      for (int k = 0; k < ka; ++k) {
        const float c = s_c[tid][k];
        if (c < m1) { m2 = m1; m1 = c; j1 = 1 + qbase + k; }
        else if (c < m2) m2 = c;
      }
      for (int k = 64; k < kmax; ++k) {
        const float c = s_c[tid][k];
        if (c < n1) { n2 = n1; n1 = c; i1 = 1 + qbase + k; }
        else if (c < n2) n2 = c;
      }
      if (n1 < m1) { m2 = fminf(m1, n2); m1 = n1; j1 = i1; }
      else m2 = fminf(m2, n1);
      // merge chunk into running (same merge order as split Phase B, ch ascending)
      if (m1 < rm1) { rm2 = fminf(rm1, m2); rm1 = m1; rj1 = j1; }
      else rm2 = fminf(rm2, m1);
    }
    __syncthreads();
  }
  __threadfence_block();   // cost writes -> visible to wave-0 reads in Phase D

  // ---- Phase C: greedy claim, contested columns go to max regret ----
  if (tid < n) {
    const float regret = rm2 - rm1;        // >= 0: non-neg f32 bits are monotone
    const unsigned long long key =
        ((unsigned long long)__float_as_uint(regret) << 20) | (unsigned long long)(tid + 1);
    atomicMax(&way64[rj1], key);
  }
  __syncthreads();
  if (tid < n) {
    if ((int)(way64[rj1] & 0xFFFFFu) == tid + 1) {  // winner: vl[j1] = m1 - m2 (<= 0)
      p[rj1] = tid + 1;
      vl[rj1] = rm1 - rm2;
    } else {                                        // loser: queue for ARR
      const int t0 = atomicAdd(&sh_qtail, 1);
      queue[t0 & QMASK] = tid + 1;
    }
  }
  __syncthreads();

  // ---- Phase D: single-wave ARR, register duals, 3-deep row prefetch pipeline ----
  if (w == 0) {
    float v[KPL];
#pragma unroll
    for (int k = 0; k < KPL; ++k) v[k] = vl[1 + lane + (k << 6)];
    int head = 0, tail = sh_qtail, rounds = 0;

    float bufA[KPL], bufB[KPL], bufC[KPL];
    int ia = -1, ib = -1, ic = -1;

    auto loadrow = [&](float* buf, int rid) {
      const float* Cr = Cb + (size_t)(rid - 1) * STRIDE + lane;
#pragma unroll
      for (int k = 0; k < KPL; ++k) buf[k] = Cr[k << 6];
    };
    auto do_step = [&](float* rc, int i) {
      float m1 = 3e38f, m2 = 3e38f, n1 = 3e38f, n2 = 3e38f;
      int j1 = 0x7FFFFFFF, i1 = 0x7FFFFFFF;
#pragma unroll
      for (int k = 0; k < 8; ++k) {
        const float c = rc[k] - v[k];
        if (c < m1) { m2 = m1; m1 = c; j1 = 1 + lane + (k << 6); }
        else if (c < m2) m2 = c;
      }
#pragma unroll
      for (int k = 8; k < KPL; ++k) {
        const float c = rc[k] - v[k];
        if (c < n1) { n2 = n1; n1 = c; i1 = 1 + lane + (k << 6); }
        else if (c < n2) n2 = c;
      }
      if (n1 < m1) { m2 = fminf(m1, n2); m1 = n1; j1 = i1; }
      else m2 = fminf(m2, n1);
      for (int m = 1; m < 64; m <<= 1) {
        const float o1 = __shfl_xor(m1, m);
        const float o2 = __shfl_xor(m2, m);
        const int oj = __shfl_xor(j1, m);
        if (o1 < m1) { m2 = fminf(m1, o2); m1 = o1; j1 = oj; }
        else m2 = fminf(m2, o1);
      }
      float d = m2 - m1;
      if (d < 0.f) d = 0.f;
      const int c0 = j1 - 1;
      if ((c0 & 63) == lane) {   // strict decrease of claimed column's dual
        const int kk = c0 >> 6;
        const float ov = v[kk];
        float nv = ov - d;
        if (!(nv < ov)) nv = nextafterf(ov, -3e38f);
        v[kk] = nv;
      }
      const int k0 = p[j1];      // broadcast LDS read
      p[j1] = i;                 // same-addr write, one lane wins
      head++;
      if (k0 > 0) {
        if (lane == 0) queue[tail & QMASK] = k0;
        tail++;
      }
    };

    if (head < tail)     { ia = queue[head & QMASK];       loadrow(bufA, ia); }
    if (head + 1 < tail) { ib = queue[(head + 1) & QMASK]; loadrow(bufB, ib); }
    if (head + 2 < tail) { ic = queue[(head + 2) & QMASK]; loadrow(bufC, ic); }

    while (head < tail && rounds < ROUND_CAP) {
      if (ia < 0) { ia = queue[head & QMASK]; loadrow(bufA, ia); }
      do_step(bufA, ia);
      ia = -1;
      if (head + 2 < tail) { ia = queue[(head + 2) & QMASK]; loadrow(bufA, ia); }
      rounds++;
      if (!(head < tail && rounds < ROUND_CAP)) break;
      if (ib < 0) { ib = queue[head & QMASK]; loadrow(bufB, ib); }
      do_step(bufB, ib);
      ib = -1;
      if (head + 2 < tail) { ib = queue[(head + 2) & QMASK]; loadrow(bufB, ib); }
      rounds++;
      if (!(head < tail && rounds < ROUND_CAP)) break;
      if (ic < 0) { ic = queue[head & QMASK]; loadrow(bufC, ic); }
      do_step(bufC, ic);
      ic = -1;
      if (head + 2 < tail) { ic = queue[(head + 2) & QMASK]; loadrow(bufC, ic); }
      rounds++;
    }
  }
  __syncthreads();

  // ---- Phase E: fused loss; softmax stats from Phase A, 1 gather per query ----
  double wnll = 0.0, wt = 0.0, l1d = 0.0, gld = 0.0;
  int nm = 0;
  for (int q = tid; q < QQ; q += NT) {
    const int idx = b * QQ + q;
    const int g = p[q + 1] - 1;   // row -> gt index (valid gts are a prefix)
    const int t = (g >= 0) ? s_gc[g] : NCLS;
    const float lt = logits[(size_t)idx * CP1 + t];
    const float logp = (lt - s_mx[q]) - s_lse[q];
    const float wgt = (t == NCLS) ? 0.1f : 1.0f;
    wnll += (double)(wgt * (-logp));
    wt += (double)wgt;
    if (g >= 0) {
      nm += 1;
      const float* pb = pboxes + (size_t)idx * 4;
      const float* gb = gboxes + ((size_t)b * GG + g) * 4;
      const float pcx = pb[0], pcy = pb[1], pw = pb[2], ph = pb[3];
      const float gcx = gb[0], gcy = gb[1], gw = gb[2], gh = gb[3];
      const float l1 = fabsf(pcx - gcx) + fabsf(pcy - gcy) + fabsf(pw - gw) + fabsf(ph - gh);
      const float px1 = pcx - 0.5f * pw, py1 = pcy - 0.5f * ph;
      const float px2 = pcx + 0.5f * pw, py2 = pcy + 0.5f * ph;
      const float gx1 = gcx - 0.5f * gw, gy1 = gcy - 0.5f * gh;
      const float gx2 = gcx + 0.5f * gw, gy2 = gcy + 0.5f * gh;
      const float pa = fmaxf(px2 - px1, 0.f) * fmaxf(py2 - py1, 0.f);
      const float ga = fmaxf(gx2 - gx1, 0.f) * fmaxf(gy2 - gy1, 0.f);
      const float ltx = fmaxf(px1, gx1), lty = fmaxf(py1, gy1);
      const float rbx = fminf(px2, gx2), rby = fminf(py2, gy2);
      const float iw = fmaxf(rbx - ltx, 0.f), ih = fmaxf(rby - lty, 0.f);
      const float inter = iw * ih;
      const float uni = pa + ga - inter;
      const float iou = inter / fmaxf(uni, 1e-6f);
      const float ex1 = fminf(px1, gx1), ey1 = fminf(py1, gy1);
      const float ex2 = fmaxf(px2, gx2), ey2 = fmaxf(py2, gy2);
      const float ew = fmaxf(ex2 - ex1, 0.f), eh = fmaxf(ey2 - ey1, 0.f);
      const float enc = ew * eh;
      const float giou = iou - (enc - uni) / fmaxf(enc, 1e-6f);
      l1d += (double)l1;
      gld += (double)(1.0f - giou);
    }
  }

  for (int off = 32; off; off >>= 1) {
    wnll += __shfl_down(wnll, off);
    wt   += __shfl_down(wt, off);
    l1d  += __shfl_down(l1d, off);
    gld  += __shfl_down(gld, off);
    nm   += __shfl_down(nm, off);
  }
  if (lane == 0) { r0[w] = wnll; r1[w] = wt; r2[w] = l1d; r3[w] = gld; r4[w] = nm; }
  __syncthreads();
  if (tid == 0) {
    for (int x = 1; x < NW; ++x) { wnll += r0[x]; wt += r1[x]; l1d += r2[x]; gld += r3[x]; nm += r4[x]; }
    atomicAdd(&acc->wnll, wnll);
    atomicAdd(&acc->wt, wt);
    atomicAdd(&acc->l1, l1d);
    atomicAdd(&acc->gl, gld);
    atomicAdd(&acc->nm, nm);
    __threadfence();
    const int ticket = atomicAdd(&acc->counter, 1);
    if (ticket == BB - 1) {
      const double fw = atomicAdd(&acc->wnll, 0.0);
      const double fwt = atomicAdd(&acc->wt, 0.0);
      const double fl1 = atomicAdd(&acc->l1, 0.0);
      const double fgl = atomicAdd(&acc->gl, 0.0);
      int fnm = atomicAdd(&acc->nm, 0);
      if (fnm < 1) fnm = 1;
      const double loss = (double)CLS_W * (fw / fwt) +
                          ((double)L1_W * fl1 + (double)GIOU_W * fgl) / (double)fnm;
      out[0] = (float)loss;
    }
  }
}

extern "C" void kernel_launch(void* const* d_in, const int* in_sizes, int n_in,
                              void* d_out, int out_size, void* d_ws, size_t ws_size,
                              hipStream_t stream) {
  const float* logits = (const float*)d_in[0];
  const float* pboxes = (const float*)d_in[1];
  const int*   gcls   = (const int*)d_in[2];
  const float* gboxes = (const float*)d_in[3];

  char* ws = (char*)d_ws;
  Accum* acc = (Accum*)ws;                 // zeroed by the memset below each iteration
  float* cost = (float*)(ws + 4096);       // B*G*960 floats ~ 24.6 MB

  hipMemsetAsync(acc, 0, 256, stream);     // graph-capturable stream op (same as harness fills)
  fused_kernel<<<BB, NT, 0, stream>>>(logits, pboxes, gcls, gboxes, cost, acc, (float*)d_out);
}

// Round 3
// 105.010 us; speedup vs baseline: 1.9364x; 1.9364x over previous
//
#include <hip/hip_runtime.h>
#include <hip/hip_bf16.h>
#include <math.h>

#define BB 64
#define QQ 900
#define GG 100
#define NCLS 10
#define CP1 11

#define STRIDE 960   // 64*15: every lane owns exactly KPL columns; cols 900..959 are +inf pads
#define KPL 15
#define NT 512
#define NW 8
#define QMASK 255    // ring queue; live entries <= n + NW <= 108 < 256
#define ROUND_CAP 20000

#define NCH 8        // q-chunks in cost kernel
#define QCH 128      // queries per chunk (8*128 = 1024 covers 960 stride)

#define CLS_W 2.0f
#define L1_W 5.0f
#define GIOU_W 2.0f

struct Accum {
  double wnll, wt, l1, gl;
  int nm, counter;
  int pad[6];
};

// ---------------- cost matrix + per-chunk row-min partials ----------------
// grid (NCH, BB) x 256 threads. Threads split as 128 q x 2 interleaved g-halves
// (g = gh, gh+2, ... -> balanced for any n). Rows g >= n are never computed or
// written (jv never reads them). Each block emits per-row (m1, m2, argmin) over
// its q-chunk via an LDS transpose (+1 pad -> conflict-free) + serial scan.
__global__ __launch_bounds__(256) void cost_kernel(
    const float* __restrict__ logits, const float* __restrict__ pboxes,
    const int* __restrict__ gcls, const float* __restrict__ gboxes,
    float* __restrict__ cost, float4* __restrict__ part, Accum* acc) {
  const int b = blockIdx.y;
  const int chunk = blockIdx.x;
  const int tid = threadIdx.x;
  const int ql = tid & (QCH - 1);
  const int gh = tid >> 7;               // 0/1: interleaved half (g = gh + 2i)
  const int q = chunk * QCH + ql;

  if (chunk == 0 && b == 0 && tid == 0) {
    acc->wnll = 0.0; acc->wt = 0.0; acc->l1 = 0.0; acc->gl = 0.0;
    acc->nm = 0; acc->counter = 0;
  }

  __shared__ float s_gb[GG * 4];
  __shared__ int   s_gc[GG];
  __shared__ float s_prob[QCH * 13];
  __shared__ float s_c[GG][QCH + 1];     // +1 pad: conflict-free both axes
  __shared__ int   sh_n;

  if (tid == 0) sh_n = 0;
  __syncthreads();

  for (int i = tid; i < GG * 4; i += 256) s_gb[i] = gboxes[b * GG * 4 + i];
  for (int i = tid; i < GG; i += 256) {
    const int v = gcls[b * GG + i];
    s_gc[i] = v;
    if (v >= 0) atomicAdd(&sh_n, 1);
  }

  float pcx = 0.f, pcy = 0.f, pw = 0.f, ph = 0.f;
  if (q < QQ) {
    const float* pb = pboxes + ((size_t)b * QQ + q) * 4;
    pcx = pb[0]; pcy = pb[1]; pw = pb[2]; ph = pb[3];
    if (gh == 0) {  // softmax once per q, shared with the other g-half
      const float* lg = logits + ((size_t)b * QQ + q) * CP1;
      float l[CP1];
      float mx = -1e30f;
      for (int c = 0; c < CP1; ++c) { l[c] = lg[c]; mx = fmaxf(mx, l[c]); }
      float se = 0.f;
      for (int c = 0; c < CP1; ++c) { l[c] = expf(l[c] - mx); se += l[c]; }
      const float inv = 1.0f / se;
      for (int c = 0; c < NCLS; ++c) s_prob[ql * 13 + c] = l[c] * inv;
    }
  }
  __syncthreads();
  const int sn = sh_n;

  const float px1 = pcx - 0.5f * pw, py1 = pcy - 0.5f * ph;
  const float px2 = pcx + 0.5f * pw, py2 = pcy + 0.5f * ph;
  const float pa = fmaxf(px2 - px1, 0.f) * fmaxf(py2 - py1, 0.f);

  float* crow = cost + ((size_t)b * GG) * STRIDE + q;
  for (int g = gh; g < sn; g += 2) {     // interleave: both halves busy for any n
    float cv = 3e38f;
    if (q < QQ) {
      int cls = s_gc[g];
      cls = cls < 0 ? 0 : (cls > NCLS - 1 ? NCLS - 1 : cls);
      const float cc = -s_prob[ql * 13 + cls];
      const float gcx = s_gb[g * 4 + 0], gcy = s_gb[g * 4 + 1];
      const float gw  = s_gb[g * 4 + 2], gh2 = s_gb[g * 4 + 3];
      const float l1 = fabsf(pcx - gcx) + fabsf(pcy - gcy) + fabsf(pw - gw) + fabsf(ph - gh2);
      const float gx1 = gcx - 0.5f * gw, gy1 = gcy - 0.5f * gh2;
      const float gx2 = gcx + 0.5f * gw, gy2 = gcy + 0.5f * gh2;
      const float ga = fmaxf(gx2 - gx1, 0.f) * fmaxf(gy2 - gy1, 0.f);
      const float ltx = fmaxf(px1, gx1), lty = fmaxf(py1, gy1);
      const float rbx = fminf(px2, gx2), rby = fminf(py2, gy2);
      const float iw = fmaxf(rbx - ltx, 0.f), ih = fmaxf(rby - lty, 0.f);
      const float inter = iw * ih;
      const float uni = pa + ga - inter;
      const float iou = inter / fmaxf(uni, 1e-6f);
      const float ex1 = fminf(px1, gx1), ey1 = fminf(py1, gy1);
      const float ex2 = fmaxf(px2, gx2), ey2 = fmaxf(py2, gy2);
      const float ew = fmaxf(ex2 - ex1, 0.f), eh = fmaxf(ey2 - ey1, 0.f);
      const float enc = ew * eh;
      const float giou = iou - (enc - uni) / fmaxf(enc, 1e-6f);
      cv = CLS_W * cc + L1_W * l1 - GIOU_W * giou;
      crow[(size_t)g * STRIDE] = cv;
    } else if (q < STRIDE) {
      crow[(size_t)g * STRIDE] = 1e30f;   // pad columns: Phase D scans them
    }
    s_c[g][ql] = cv;                       // 3e38 beyond QQ: excluded from mins
  }
  __syncthreads();

  // per-row (m1, m2, argmin) over this chunk: thread t = row, serial scan, 2 ILP chains
  if (tid < sn) {
    const int kmax = (chunk == NCH - 1) ? (QQ - (NCH - 1) * QCH) : QCH;  // 4 or 128
    float m1 = 3e38f, m2 = 3e38f, n1 = 3e38f, n2 = 3e38f;
    int j1 = 0x7FFFFFFF, i1 = 0x7FFFFFFF;
    const int ka = kmax < 64 ? kmax : 64;
    for (int k = 0; k < ka; ++k) {
      const float c = s_c[tid][k];
      if (c < m1) { m2 = m1; m1 = c; j1 = 1 + chunk * QCH + k; }
      else if (c < m2) m2 = c;
    }
    for (int k = 64; k < kmax; ++k) {
      const float c = s_c[tid][k];
      if (c < n1) { n2 = n1; n1 = c; i1 = 1 + chunk * QCH + k; }
      else if (c < n2) n2 = c;
    }
    if (n1 < m1) { m2 = fminf(m1, n2); m1 = n1; j1 = i1; }
    else m2 = fminf(m2, n1);
    part[((size_t)b * NCH + chunk) * QCH + tid] = make_float4(m1, m2, __int_as_float(j1), 0.f);
  }
}

// ---------------- jv: partial rowmin + regret-greedy + Jacobi auction + fused loss ----
__global__ __launch_bounds__(NT) void jv_kernel(
    const float* __restrict__ logits, const float* __restrict__ pboxes,
    const int* __restrict__ gcls, const float* __restrict__ gboxes,
    const float* __restrict__ cost, const float4* __restrict__ part,
    Accum* acc, float* out) {
  const int b = blockIdx.x;
  const int tid = threadIdx.x;
  const int lane = tid & 63;
  const int w = tid >> 6;

  __shared__ float vl[STRIDE + 2];      // column duals (f32), <= 0 — live copy for all waves
  __shared__ int   p[QQ + 1];           // column -> owning row (1-based), 0 = free
  __shared__ unsigned long long way64[STRIDE + 2];  // regret-max claim keys
  __shared__ float m1l[GG + 1], m2l[GG + 1];
  __shared__ int   aminl[GG + 1];
  __shared__ int   s_gc[GG];
  __shared__ int   queue[QMASK + 1];
  __shared__ int   sh_n, sh_qtail, sh_head;
  __shared__ double r0[NW], r1[NW], r2[NW], r3[NW];
  __shared__ int r4[NW];
  __shared__ float s_lse[QQ], s_mx[QQ];  // Phase-E softmax stats

  if (tid == 0) { sh_n = 0; sh_qtail = 0; sh_head = 0; }
  for (int j = tid; j <= QQ; j += NT) p[j] = 0;
  for (int j = tid; j < STRIDE + 2; j += NT) { vl[j] = 0.f; way64[j] = 0ull; }
  if (tid < GG) s_gc[tid] = gcls[b * GG + tid];
  __syncthreads();
  if (tid < GG && s_gc[tid] >= 0) atomicAdd(&sh_n, 1);
  __syncthreads();
  const int n = sh_n;
  const float* Cb = cost + (size_t)b * GG * STRIDE;

  // ---- Phase B: combine per-chunk partials from cost_kernel ----
  for (int r = tid; r < n; r += NT) {
    float m1 = 3e38f, m2 = 3e38f;
    int j1 = 0x7FFFFFFF;
#pragma unroll
    for (int ch = 0; ch < NCH; ++ch) {
      const float4 pr = part[((size_t)b * NCH + ch) * QCH + r];
      const float pm1 = pr.x, pm2 = pr.y;
      if (pm1 < m1) { m2 = fminf(m1, pm2); m1 = pm1; j1 = __float_as_int(pr.z); }
      else m2 = fminf(m2, pm1);
    }
    m1l[r] = m1; m2l[r] = m2; aminl[r] = j1;
  }
  // softmax stats for Phase E (same inner op order as round-1 -> bit-identical logp)
  for (int qq = tid; qq < QQ; qq += NT) {
    const float* lg = logits + ((size_t)b * QQ + qq) * CP1;
    float l[CP1];
    float mx = -1e30f;
    for (int c = 0; c < CP1; ++c) { l[c] = lg[c]; mx = fmaxf(mx, l[c]); }
    float se = 0.f;
    for (int c = 0; c < CP1; ++c) se += expf(l[c] - mx);
    s_mx[qq] = mx;
    s_lse[qq] = logf(se);
  }
  __syncthreads();

  // ---- Phase C: greedy claim, contested columns go to max regret ----
  if (tid < n) {
    const float regret = m2l[tid] - m1l[tid];   // >= 0: non-neg f32 bits are monotone
    const unsigned long long key =
        ((unsigned long long)__float_as_uint(regret) << 20) | (unsigned long long)(tid + 1);
    atomicMax(&way64[aminl[tid]], key);
  }
  __syncthreads();
  if (tid < n) {
    const int j1 = aminl[tid];
    if ((int)(way64[j1] & 0xFFFFFu) == tid + 1) {  // winner: vl[j1] = m1 - m2 (<= 0)
      p[j1] = tid + 1;
      vl[j1] = m1l[tid] - m2l[tid];
    } else {                                       // loser: queue for the auction
      const int t0 = atomicAdd(&sh_qtail, 1);
      queue[t0 & QMASK] = tid + 1;
    }
  }
  __syncthreads();

  // ---- Phase D: Jacobi auction — up to NW queued rows bid per round, one per wave.
  // Each winner maintains complementary slackness vs the same dual snapshot
  // (updates touch distinct columns -> commute); losers requeue and rescan.
  // Same math as the serial Gauss-Seidel auction, just batched.
  {
    float pf[KPL];
    int pf_ok = 0, pf_rid = 0;
    int rounds = 0;
    while (rounds < ROUND_CAP) {
      const int head = sh_head, tail = sh_qtail;   // uniform: read after barrier
      const int nq = tail - head;
      if (nq <= 0) break;
      const int take = nq < NW ? nq : NW;
      float m1 = 3e38f, m2 = 3e38f;
      int j1 = 0x7FFFFFFF, rid = 0;
      if (w < take) {
        float rc[KPL];
        if (pf_ok) {       // prefetched last round: position head+w guaranteed match
          rid = pf_rid;
#pragma unroll
          for (int k = 0; k < KPL; ++k) rc[k] = pf[k];
        } else {
          rid = queue[(head + w) & QMASK];
          const float* Cr = Cb + (size_t)(rid - 1) * STRIDE + lane;
#pragma unroll
          for (int k = 0; k < KPL; ++k) rc[k] = Cr[k << 6];
        }
        float n1 = 3e38f, n2 = 3e38f;
        int i1 = 0x7FFFFFFF;
#pragma unroll
        for (int k = 0; k < 8; ++k) {
          const float c = rc[k] - vl[1 + lane + (k << 6)];
          if (c < m1) { m2 = m1; m1 = c; j1 = 1 + lane + (k << 6); }
          else if (c < m2) m2 = c;
        }
#pragma unroll
        for (int k = 8; k < KPL; ++k) {
          const float c = rc[k] - vl[1 + lane + (k << 6)];
          if (c < n1) { n2 = n1; n1 = c; i1 = 1 + lane + (k << 6); }
          else if (c < n2) n2 = c;
        }
        if (n1 < m1) { m2 = fminf(m1, n2); m1 = n1; j1 = i1; }
        else m2 = fminf(m2, n1);
        for (int m = 1; m < 64; m <<= 1) {
          const float o1 = __shfl_xor(m1, m);
          const float o2 = __shfl_xor(m2, m);
          const int oj = __shfl_xor(j1, m);
          if (o1 < m1) { m2 = fminf(m1, o2); m1 = o1; j1 = oj; }
          else m2 = fminf(m2, o1);
        }
      }
      // speculative prefetch of next round's row (queue entries < tail are immutable;
      // next round's slot for wave w is exactly head+take+w)
      pf_ok = 0;
      const int npos = head + take + w;
      if (npos < tail) {
        pf_rid = queue[npos & QMASK];
        const float* Cr = Cb + (size_t)(pf_rid - 1) * STRIDE + lane;
#pragma unroll
        for (int k = 0; k < KPL; ++k) pf[k] = Cr[k << 6];
        pf_ok = 1;
      }
      if (take > 1) {   // claim resolution needed only when multiple bidders
        if (w < take && lane == 0) way64[j1] = 0ull;   // reset this round's slots
        __syncthreads();
        if (w < take && lane == 0) {
          float d = m2 - m1;
          if (d < 0.f) d = 0.f;
          const unsigned long long key =
              ((unsigned long long)__float_as_uint(d) << 20) | (unsigned long long)rid;
          atomicMax(&way64[j1], key);
        }
        __syncthreads();
      }
      if (w < take && lane == 0) {
        if (take == 1 || (int)(way64[j1] & 0xFFFFFu) == rid) {   // winner
          float d = m2 - m1;
          if (d < 0.f) d = 0.f;
          const float ov = vl[j1];
          float nv = ov - d;
          if (!(nv < ov)) nv = nextafterf(ov, -3e38f);   // strict decrease
          vl[j1] = nv;
          const int k0 = p[j1];
          p[j1] = rid;
          if (k0 > 0) { const int t0 = atomicAdd(&sh_qtail, 1); queue[t0 & QMASK] = k0; }
        } else {                                         // loser: requeue, rescan next round
          const int t0 = atomicAdd(&sh_qtail, 1);
          queue[t0 & QMASK] = rid;
        }
      }
      if (tid == 0) sh_head = head + take;
      ++rounds;
      __syncthreads();
    }
  }
  __syncthreads();

  // ---- Phase E: fused loss; softmax stats precomputed, 1 gather per query ----
  double wnll = 0.0, wt = 0.0, l1d = 0.0, gld = 0.0;
  int nm = 0;
  for (int q = tid; q < QQ; q += NT) {
    const int idx = b * QQ + q;
    const int g = p[q + 1] - 1;   // row -> gt index (valid gts are a prefix)
    const int t = (g >= 0) ? s_gc[g] : NCLS;
    const float lt = logits[(size_t)idx * CP1 + t];
    const float logp = (lt - s_mx[q]) - s_lse[q];
    const float wgt = (t == NCLS) ? 0.1f : 1.0f;
    wnll += (double)(wgt * (-logp));
    wt += (double)wgt;
    if (g >= 0) {
      nm += 1;
      const float* pb = pboxes + (size_t)idx * 4;
      const float* gb = gboxes + ((size_t)b * GG + g) * 4;
      const float pcx = pb[0], pcy = pb[1], pw = pb[2], ph = pb[3];
      const float gcx = gb[0], gcy = gb[1], gw = gb[2], gh = gb[3];
      const float l1 = fabsf(pcx - gcx) + fabsf(pcy - gcy) + fabsf(pw - gw) + fabsf(ph - gh);
      const float px1 = pcx - 0.5f * pw, py1 = pcy - 0.5f * ph;
      const float px2 = pcx + 0.5f * pw, py2 = pcy + 0.5f * ph;
      const float gx1 = gcx - 0.5f * gw, gy1 = gcy - 0.5f * gh;
      const float gx2 = gcx + 0.5f * gw, gy2 = gcy + 0.5f * gh;
      const float pa = fmaxf(px2 - px1, 0.f) * fmaxf(py2 - py1, 0.f);
      const float ga = fmaxf(gx2 - gx1, 0.f) * fmaxf(gy2 - gy1, 0.f);
      const float ltx = fmaxf(px1, gx1), lty = fmaxf(py1, gy1);
      const float rbx = fminf(px2, gx2), rby = fminf(py2, gy2);
      const float iw = fmaxf(rbx - ltx, 0.f), ih = fmaxf(rby - lty, 0.f);
      const float inter = iw * ih;
      const float uni = pa + ga - inter;
      const float iou = inter / fmaxf(uni, 1e-6f);
      const float ex1 = fminf(px1, gx1), ey1 = fminf(py1, gy1);
      const float ex2 = fmaxf(px2, gx2), ey2 = fmaxf(py2, gy2);
      const float ew = fmaxf(ex2 - ex1, 0.f), eh = fmaxf(ey2 - ey1, 0.f);
      const float enc = ew * eh;
      const float giou = iou - (enc - uni) / fmaxf(enc, 1e-6f);
      l1d += (double)l1;
      gld += (double)(1.0f - giou);
    }
  }

  for (int off = 32; off; off >>= 1) {
    wnll += __shfl_down(wnll, off);
    wt   += __shfl_down(wt, off);
    l1d  += __shfl_down(l1d, off);
    gld  += __shfl_down(gld, off);
    nm   += __shfl_down(nm, off);
  }
  if (lane == 0) { r0[w] = wnll; r1[w] = wt; r2[w] = l1d; r3[w] = gld; r4[w] = nm; }
  __syncthreads();
  if (tid == 0) {
    for (int x = 1; x < NW; ++x) { wnll += r0[x]; wt += r1[x]; l1d += r2[x]; gld += r3[x]; nm += r4[x]; }
    atomicAdd(&acc->wnll, wnll);
    atomicAdd(&acc->wt, wt);
    atomicAdd(&acc->l1, l1d);
    atomicAdd(&acc->gl, gld);
    atomicAdd(&acc->nm, nm);
    __threadfence();
    const int ticket = atomicAdd(&acc->counter, 1);
    if (ticket == BB - 1) {
      const double fw = atomicAdd(&acc->wnll, 0.0);
      const double fwt = atomicAdd(&acc->wt, 0.0);
      const double fl1 = atomicAdd(&acc->l1, 0.0);
      const double fgl = atomicAdd(&acc->gl, 0.0);
      int fnm = atomicAdd(&acc->nm, 0);
      if (fnm < 1) fnm = 1;
      const double loss = (double)CLS_W * (fw / fwt) +
                          ((double)L1_W * fl1 + (double)GIOU_W * fgl) / (double)fnm;
      out[0] = (float)loss;
    }
  }
}

extern "C" void kernel_launch(void* const* d_in, const int* in_sizes, int n_in,
                              void* d_out, int out_size, void* d_ws, size_t ws_size,
                              hipStream_t stream) {
  const float* logits = (const float*)d_in[0];
  const float* pboxes = (const float*)d_in[1];
  const int*   gcls   = (const int*)d_in[2];
  const float* gboxes = (const float*)d_in[3];

  char* ws = (char*)d_ws;
  Accum* acc = (Accum*)ws;                                  // 64 B, inited in cost_kernel
  float4* part = (float4*)(ws + 4096);                      // 64*8*128 float4 = 1 MB
  float* cost = (float*)(ws + 4096 + (size_t)BB * NCH * QCH * sizeof(float4));  // ~24.6 MB

  cost_kernel<<<dim3(NCH, BB), 256, 0, stream>>>(logits, pboxes, gcls, gboxes, cost, part, acc);
  jv_kernel<<<BB, NT, 0, stream>>>(logits, pboxes, gcls, gboxes, cost, part, acc, (float*)d_out);
}

// Round 4
// 104.290 us; speedup vs baseline: 1.9498x; 1.0069x over previous
//
#include <hip/hip_runtime.h>
#include <hip/hip_bf16.h>
#include <math.h>

#define BB 64
#define QQ 900
#define GG 100
#define NCLS 10
#define CP1 11

#define STRIDE 960   // 64*15: every lane owns exactly KPL columns; cols 900..959 are +inf pads
#define KPL 15
#define NT 512
#define NW 8
#define QMASK 255    // ring queue; live entries <= n + 16 <= 116 < 256
#define ROUND_CAP 20000

#define NCH 8        // q-chunks in cost kernel
#define QCH 128      // queries per chunk (8*128 = 1024 covers 960 stride)

#define CLS_W 2.0f
#define L1_W 5.0f
#define GIOU_W 2.0f

struct Accum {
  double wnll, wt, l1, gl;
  int nm, counter;
  int pad[6];
};

// ---------------- cost matrix + per-chunk row-min partials ----------------
// grid (NCH, BB) x 256 threads. Threads split as 128 q x 2 interleaved g-halves
// (g = gh, gh+2, ... -> balanced for any n). Rows g >= n are never computed or
// written (jv never reads them). Chunk row-min scan split into two 64-deep
// half-chains on 2x128 threads + exact strict-less merge -> bit-identical to
// the single 128-deep serial scan.
__global__ __launch_bounds__(256) void cost_kernel(
    const float* __restrict__ logits, const float* __restrict__ pboxes,
    const int* __restrict__ gcls, const float* __restrict__ gboxes,
    float* __restrict__ cost, float4* __restrict__ part, Accum* acc) {
  const int b = blockIdx.y;
  const int chunk = blockIdx.x;
  const int tid = threadIdx.x;
  const int ql = tid & (QCH - 1);
  const int gh = tid >> 7;               // 0/1: interleaved half (g = gh + 2i)
  const int q = chunk * QCH + ql;

  if (chunk == 0 && b == 0 && tid == 0) {
    acc->wnll = 0.0; acc->wt = 0.0; acc->l1 = 0.0; acc->gl = 0.0;
    acc->nm = 0; acc->counter = 0;
  }

  __shared__ float s_gb[GG * 4];
  __shared__ int   s_gc[GG];
  __shared__ float s_prob[QCH * 13];
  __shared__ float s_c[GG][QCH + 1];     // +1 pad: conflict-free both axes
  __shared__ float pm1[2][GG], pm2[2][GG];
  __shared__ int   pj1[2][GG];
  __shared__ int   sh_n;

  if (tid == 0) sh_n = 0;
  __syncthreads();

  for (int i = tid; i < GG * 4; i += 256) s_gb[i] = gboxes[b * GG * 4 + i];
  for (int i = tid; i < GG; i += 256) {
    const int v = gcls[b * GG + i];
    s_gc[i] = v;
    if (v >= 0) atomicAdd(&sh_n, 1);
  }

  float pcx = 0.f, pcy = 0.f, pw = 0.f, ph = 0.f;
  if (q < QQ) {
    const float* pb = pboxes + ((size_t)b * QQ + q) * 4;
    pcx = pb[0]; pcy = pb[1]; pw = pb[2]; ph = pb[3];
    if (gh == 0) {  // softmax once per q, shared with the other g-half
      const float* lg = logits + ((size_t)b * QQ + q) * CP1;
      float l[CP1];
      float mx = -1e30f;
      for (int c = 0; c < CP1; ++c) { l[c] = lg[c]; mx = fmaxf(mx, l[c]); }
      float se = 0.f;
      for (int c = 0; c < CP1; ++c) { l[c] = expf(l[c] - mx); se += l[c]; }
      const float inv = 1.0f / se;
      for (int c = 0; c < NCLS; ++c) s_prob[ql * 13 + c] = l[c] * inv;
    }
  }
  __syncthreads();
  const int sn = sh_n;

  const float px1 = pcx - 0.5f * pw, py1 = pcy - 0.5f * ph;
  const float px2 = pcx + 0.5f * pw, py2 = pcy + 0.5f * ph;
  const float pa = fmaxf(px2 - px1, 0.f) * fmaxf(py2 - py1, 0.f);

  float* crow = cost + ((size_t)b * GG) * STRIDE + q;
  for (int g = gh; g < sn; g += 2) {     // interleave: both halves busy for any n
    float cv = 3e38f;
    if (q < QQ) {
      int cls = s_gc[g];
      cls = cls < 0 ? 0 : (cls > NCLS - 1 ? NCLS - 1 : cls);
      const float cc = -s_prob[ql * 13 + cls];
      const float gcx = s_gb[g * 4 + 0], gcy = s_gb[g * 4 + 1];
      const float gw  = s_gb[g * 4 + 2], gh2 = s_gb[g * 4 + 3];
      const float l1 = fabsf(pcx - gcx) + fabsf(pcy - gcy) + fabsf(pw - gw) + fabsf(ph - gh2);
      const float gx1 = gcx - 0.5f * gw, gy1 = gcy - 0.5f * gh2;
      const float gx2 = gcx + 0.5f * gw, gy2 = gcy + 0.5f * gh2;
      const float ga = fmaxf(gx2 - gx1, 0.f) * fmaxf(gy2 - gy1, 0.f);
      const float ltx = fmaxf(px1, gx1), lty = fmaxf(py1, gy1);
      const float rbx = fminf(px2, gx2), rby = fminf(py2, gy2);
      const float iw = fmaxf(rbx - ltx, 0.f), ih = fmaxf(rby - lty, 0.f);
      const float inter = iw * ih;
      const float uni = pa + ga - inter;
      const float iou = inter / fmaxf(uni, 1e-6f);
      const float ex1 = fminf(px1, gx1), ey1 = fminf(py1, gy1);
      const float ex2 = fmaxf(px2, gx2), ey2 = fmaxf(py2, gy2);
      const float ew = fmaxf(ex2 - ex1, 0.f), eh = fmaxf(ey2 - ey1, 0.f);
      const float enc = ew * eh;
      const float giou = iou - (enc - uni) / fmaxf(enc, 1e-6f);
      cv = CLS_W * cc + L1_W * l1 - GIOU_W * giou;
      crow[(size_t)g * STRIDE] = cv;
    } else if (q < STRIDE) {
      crow[(size_t)g * STRIDE] = 1e30f;   // pad columns: Phase D scans them
    }
    s_c[g][ql] = cv;                       // 3e38 beyond QQ: excluded from mins
  }
  __syncthreads();

  // split row-min scan: half 0 covers k in [0,min(kmax,64)), half 1 covers [64,kmax)
  {
    const int kmax = (chunk == NCH - 1) ? (QQ - (NCH - 1) * QCH) : QCH;  // 4 or 128
    const int half = tid >> 7;
    const int r = tid & 127;
    if (r < sn) {
      const int k0 = half ? 64 : 0;
      const int k1 = half ? kmax : (kmax < 64 ? kmax : 64);
      float m1 = 3e38f, m2 = 3e38f;
      int j1 = 0x7FFFFFFF;
      for (int k = k0; k < k1; ++k) {
        const float c = s_c[r][k];
        if (c < m1) { m2 = m1; m1 = c; j1 = 1 + chunk * QCH + k; }
        else if (c < m2) m2 = c;
      }
      pm1[half][r] = m1; pm2[half][r] = m2; pj1[half][r] = j1;
    }
    __syncthreads();
    if (tid < sn) {
      float m1 = pm1[0][tid], m2 = pm2[0][tid];
      int j1 = pj1[0][tid];
      const float n1 = pm1[1][tid], n2 = pm2[1][tid];
      const int i1 = pj1[1][tid];
      if (n1 < m1) { m2 = fminf(m1, n2); m1 = n1; j1 = i1; }   // exact same merge as before
      else m2 = fminf(m2, n1);
      part[((size_t)b * NCH + chunk) * QCH + tid] = make_float4(m1, m2, __int_as_float(j1), 0.f);
    }
  }
}

// ---------------- jv: partial rowmin + regret-greedy + 16-wide Jacobi auction + fused loss ----
__global__ __launch_bounds__(NT) void jv_kernel(
    const float* __restrict__ logits, const float* __restrict__ pboxes,
    const int* __restrict__ gcls, const float* __restrict__ gboxes,
    const float* __restrict__ cost, const float4* __restrict__ part,
    Accum* acc, float* out) {
  const int b = blockIdx.x;
  const int tid = threadIdx.x;
  const int lane = tid & 63;
  const int w = tid >> 6;

  __shared__ float vl[STRIDE + 2];      // column duals (f32), <= 0 — live copy for all waves
  __shared__ int   p[QQ + 1];           // column -> owning row (1-based), 0 = free
  __shared__ unsigned long long way64[STRIDE + 2];  // claim keys
  __shared__ float m1l[GG + 1], m2l[GG + 1];
  __shared__ int   aminl[GG + 1];
  __shared__ int   s_gc[GG];
  __shared__ int   queue[QMASK + 1];
  __shared__ int   sh_n, sh_qtail, sh_head;
  __shared__ double r0[NW], r1[NW], r2[NW], r3[NW];
  __shared__ int r4[NW];
  __shared__ float s_lse[QQ], s_mx[QQ];  // Phase-E softmax stats

  if (tid == 0) { sh_n = 0; sh_qtail = 0; sh_head = 0; }
  for (int j = tid; j <= QQ; j += NT) p[j] = 0;
  for (int j = tid; j < STRIDE + 2; j += NT) { vl[j] = 0.f; way64[j] = 0ull; }
  if (tid < GG) s_gc[tid] = gcls[b * GG + tid];
  __syncthreads();
  if (tid < GG && s_gc[tid] >= 0) atomicAdd(&sh_n, 1);
  __syncthreads();
  const int n = sh_n;
  const float* Cb = cost + (size_t)b * GG * STRIDE;

  // ---- Phase B: combine per-chunk partials from cost_kernel ----
  for (int r = tid; r < n; r += NT) {
    float m1 = 3e38f, m2 = 3e38f;
    int j1 = 0x7FFFFFFF;
#pragma unroll
    for (int ch = 0; ch < NCH; ++ch) {
      const float4 pr = part[((size_t)b * NCH + ch) * QCH + r];
      const float pm1 = pr.x, pm2 = pr.y;
      if (pm1 < m1) { m2 = fminf(m1, pm2); m1 = pm1; j1 = __float_as_int(pr.z); }
      else m2 = fminf(m2, pm1);
    }
    m1l[r] = m1; m2l[r] = m2; aminl[r] = j1;
  }
  // softmax stats for Phase E (same inner op order -> bit-identical logp)
  for (int qq = tid; qq < QQ; qq += NT) {
    const float* lg = logits + ((size_t)b * QQ + qq) * CP1;
    float l[CP1];
    float mx = -1e30f;
    for (int c = 0; c < CP1; ++c) { l[c] = lg[c]; mx = fmaxf(mx, l[c]); }
    float se = 0.f;
    for (int c = 0; c < CP1; ++c) se += expf(l[c] - mx);
    s_mx[qq] = mx;
    s_lse[qq] = logf(se);
  }
  __syncthreads();

  // ---- Phase C: greedy claim, contested columns go to max regret ----
  if (tid < n) {
    const float regret = m2l[tid] - m1l[tid];   // >= 0: non-neg f32 bits are monotone
    const unsigned long long key =
        ((unsigned long long)__float_as_uint(regret) << 20) | (unsigned long long)(tid + 1);
    atomicMax(&way64[aminl[tid]], key);
  }
  __syncthreads();
  if (tid < n) {
    const int j1 = aminl[tid];
    if ((int)(way64[j1] & 0xFFFFFu) == tid + 1) {  // winner: vl[j1] = m1 - m2 (<= 0)
      p[j1] = tid + 1;
      vl[j1] = m1l[tid] - m2l[tid];
    } else {                                       // loser: queue for the auction
      const int t0 = atomicAdd(&sh_qtail, 1);
      queue[t0 & QMASK] = tid + 1;
    }
  }
  __syncthreads();
  // zero claim keys: Phase-D round-tagged keys must start from a clean slate
  for (int j = tid; j < STRIDE + 2; j += NT) way64[j] = 0ull;
  __syncthreads();

  // ---- Phase D: 16-wide Jacobi auction — each wave bids for TWO queued rows per
  // round, sharing the vl LDS reads between both scans. All bids of a round see
  // the same dual snapshot; conflicts resolved by bid-increment-keyed atomicMax
  // with a monotone round tag (stale keys lose automatically -> no reset barrier);
  // losers requeue. Math identical to the serial auction, just batched.
  {
    float pfA[KPL], pfB[KPL];
    int pfAok = 0, pfBok = 0, pfArid = 0, pfBrid = 0;
    int kround = 0;
    while (kround < ROUND_CAP) {
      const int head = sh_head, tail = sh_qtail;   // uniform: read after barrier
      const int nq = tail - head;
      if (nq <= 0) break;
      const int take = nq < 2 * NW ? nq : 2 * NW;
      ++kround;
      const bool doA = (2 * w < take);
      const bool doB = (2 * w + 1 < take);
      int ridA = 0, ridB = 0;
      float m1A = 3e38f, m2A = 3e38f, m1B = 3e38f, m2B = 3e38f;
      int j1A = 0x7FFFFFFF, j1B = 0x7FFFFFFF;
      if (doA) {
        float rcA[KPL], rcB[KPL];
        if (pfAok) { ridA = pfArid;
#pragma unroll
          for (int k = 0; k < KPL; ++k) rcA[k] = pfA[k];
        } else {
          ridA = queue[(head + 2 * w) & QMASK];
          const float* Cr = Cb + (size_t)(ridA - 1) * STRIDE + lane;
#pragma unroll
          for (int k = 0; k < KPL; ++k) rcA[k] = Cr[k << 6];
        }
        if (doB) {
          if (pfBok) { ridB = pfBrid;
#pragma unroll
            for (int k = 0; k < KPL; ++k) rcB[k] = pfB[k];
          } else {
            ridB = queue[(head + 2 * w + 1) & QMASK];
            const float* Cr = Cb + (size_t)(ridB - 1) * STRIDE + lane;
#pragma unroll
            for (int k = 0; k < KPL; ++k) rcB[k] = Cr[k << 6];
          }
        } else {
#pragma unroll
          for (int k = 0; k < KPL; ++k) rcB[k] = 3e38f;   // inert slot
        }
        // fused scan: one vl read feeds both rows' two-chain reductions (ILP)
        float nA1 = 3e38f, nA2 = 3e38f, nB1 = 3e38f, nB2 = 3e38f;
        int iA1 = 0x7FFFFFFF, iB1 = 0x7FFFFFFF;
#pragma unroll
        for (int k = 0; k < 8; ++k) {
          const float vv = vl[1 + lane + (k << 6)];
          const float cA = rcA[k] - vv;
          if (cA < m1A) { m2A = m1A; m1A = cA; j1A = 1 + lane + (k << 6); }
          else if (cA < m2A) m2A = cA;
          const float cB = rcB[k] - vv;
          if (cB < m1B) { m2B = m1B; m1B = cB; j1B = 1 + lane + (k << 6); }
          else if (cB < m2B) m2B = cB;
        }
#pragma unroll
        for (int k = 8; k < KPL; ++k) {
          const float vv = vl[1 + lane + (k << 6)];
          const float cA = rcA[k] - vv;
          if (cA < nA1) { nA2 = nA1; nA1 = cA; iA1 = 1 + lane + (k << 6); }
          else if (cA < nA2) nA2 = cA;
          const float cB = rcB[k] - vv;
          if (cB < nB1) { nB2 = nB1; nB1 = cB; iB1 = 1 + lane + (k << 6); }
          else if (cB < nB2) nB2 = cB;
        }
        if (nA1 < m1A) { m2A = fminf(m1A, nA2); m1A = nA1; j1A = iA1; }
        else m2A = fminf(m2A, nA1);
        if (nB1 < m1B) { m2B = fminf(m1B, nB2); m1B = nB1; j1B = iB1; }
        else m2B = fminf(m2B, nB1);
        // interleaved butterflies (independent shuffle chains)
        for (int m = 1; m < 64; m <<= 1) {
          const float oA1 = __shfl_xor(m1A, m), oA2 = __shfl_xor(m2A, m);
          const int ojA = __shfl_xor(j1A, m);
          const float oB1 = __shfl_xor(m1B, m), oB2 = __shfl_xor(m2B, m);
          const int ojB = __shfl_xor(j1B, m);
          if (oA1 < m1A) { m2A = fminf(m1A, oA2); m1A = oA1; j1A = ojA; }
          else m2A = fminf(m2A, oA1);
          if (oB1 < m1B) { m2B = fminf(m1B, oB2); m1B = oB1; j1B = ojB; }
          else m2B = fminf(m2B, oB1);
        }
        if (lane == 0) {
          float dA = m2A - m1A;
          if (dA < 0.f) dA = 0.f;
          const unsigned long long keyA = ((unsigned long long)kround << 44) |
              ((unsigned long long)__float_as_uint(dA) << 12) | (unsigned long long)ridA;
          atomicMax(&way64[j1A], keyA);
          if (doB) {
            float dB = m2B - m1B;
            if (dB < 0.f) dB = 0.f;
            const unsigned long long keyB = ((unsigned long long)kround << 44) |
                ((unsigned long long)__float_as_uint(dB) << 12) | (unsigned long long)ridB;
            atomicMax(&way64[j1B], keyB);
          }
        }
      }
      // speculative prefetch for next round's fixed positions (head+take)+{2w,2w+1};
      // queue entries below the stale tail are immutable
      pfAok = 0; pfBok = 0;
      {
        const int nh = head + take;
        const int pA = nh + 2 * w, pB = pA + 1;
        if (pA < tail) {
          pfArid = queue[pA & QMASK];
          const float* Cr = Cb + (size_t)(pfArid - 1) * STRIDE + lane;
#pragma unroll
          for (int k = 0; k < KPL; ++k) pfA[k] = Cr[k << 6];
          pfAok = 1;
        }
        if (pB < tail) {
          pfBrid = queue[pB & QMASK];
          const float* Cr = Cb + (size_t)(pfBrid - 1) * STRIDE + lane;
#pragma unroll
          for (int k = 0; k < KPL; ++k) pfB[k] = Cr[k << 6];
          pfBok = 1;
        }
      }
      __syncthreads();   // all bids visible
      if (lane == 0 && doA) {
        if ((int)(way64[j1A] & 0xFFFu) == ridA) {        // winner A
          float dA = m2A - m1A;
          if (dA < 0.f) dA = 0.f;
          const float ov = vl[j1A];
          float nv = ov - dA;
          if (!(nv < ov)) nv = nextafterf(ov, -3e38f);   // strict decrease
          vl[j1A] = nv;
          const int k0 = p[j1A];
          p[j1A] = ridA;
          if (k0 > 0) { const int t0 = atomicAdd(&sh_qtail, 1); queue[t0 & QMASK] = k0; }
        } else {                                         // loser: requeue, rescan
          const int t0 = atomicAdd(&sh_qtail, 1);
          queue[t0 & QMASK] = ridA;
        }
        if (doB) {
          if ((int)(way64[j1B] & 0xFFFu) == ridB) {      // winner B
            float dB = m2B - m1B;
            if (dB < 0.f) dB = 0.f;
            const float ov = vl[j1B];
            float nv = ov - dB;
            if (!(nv < ov)) nv = nextafterf(ov, -3e38f);
            vl[j1B] = nv;
            const int k0 = p[j1B];
            p[j1B] = ridB;
            if (k0 > 0) { const int t0 = atomicAdd(&sh_qtail, 1); queue[t0 & QMASK] = k0; }
          } else {
            const int t0 = atomicAdd(&sh_qtail, 1);
            queue[t0 & QMASK] = ridB;
          }
        }
      }
      if (tid == 0) sh_head = head + take;
      __syncthreads();   // duals/p/queue stable for next round's snapshot
    }
  }
  __syncthreads();

  // ---- Phase E: fused loss; softmax stats precomputed, 1 gather per query ----
  double wnll = 0.0, wt = 0.0, l1d = 0.0, gld = 0.0;
  int nm = 0;
  for (int q = tid; q < QQ; q += NT) {
    const int idx = b * QQ + q;
    const int g = p[q + 1] - 1;   // row -> gt index (valid gts are a prefix)
    const int t = (g >= 0) ? s_gc[g] : NCLS;
    const float lt = logits[(size_t)idx * CP1 + t];
    const float logp = (lt - s_mx[q]) - s_lse[q];
    const float wgt = (t == NCLS) ? 0.1f : 1.0f;
    wnll += (double)(wgt * (-logp));
    wt += (double)wgt;
    if (g >= 0) {
      nm += 1;
      const float* pb = pboxes + (size_t)idx * 4;
      const float* gb = gboxes + ((size_t)b * GG + g) * 4;
      const float pcx = pb[0], pcy = pb[1], pw = pb[2], ph = pb[3];
      const float gcx = gb[0], gcy = gb[1], gw = gb[2], gh = gb[3];
      const float l1 = fabsf(pcx - gcx) + fabsf(pcy - gcy) + fabsf(pw - gw) + fabsf(ph - gh);
      const float px1 = pcx - 0.5f * pw, py1 = pcy - 0.5f * ph;
      const float px2 = pcx + 0.5f * pw, py2 = pcy + 0.5f * ph;
      const float gx1 = gcx - 0.5f * gw, gy1 = gcy - 0.5f * gh;
      const float gx2 = gcx + 0.5f * gw, gy2 = gcy + 0.5f * gh;
      const float pa = fmaxf(px2 - px1, 0.f) * fmaxf(py2 - py1, 0.f);
      const float ga = fmaxf(gx2 - gx1, 0.f) * fmaxf(gy2 - gy1, 0.f);
      const float ltx = fmaxf(px1, gx1), lty = fmaxf(py1, gy1);
      const float rbx = fminf(px2, gx2), rby = fminf(py2, gy2);
      const float iw = fmaxf(rbx - ltx, 0.f), ih = fmaxf(rby - lty, 0.f);
      const float inter = iw * ih;
      const float uni = pa + ga - inter;
      const float iou = inter / fmaxf(uni, 1e-6f);
      const float ex1 = fminf(px1, gx1), ey1 = fminf(py1, gy1);
      const float ex2 = fmaxf(px2, gx2), ey2 = fmaxf(py2, gy2);
      const float ew = fmaxf(ex2 - ex1, 0.f), eh = fmaxf(ey2 - ey1, 0.f);
      const float enc = ew * eh;
      const float giou = iou - (enc - uni) / fmaxf(enc, 1e-6f);
      l1d += (double)l1;
      gld += (double)(1.0f - giou);
    }
  }

  for (int off = 32; off; off >>= 1) {
    wnll += __shfl_down(wnll, off);
    wt   += __shfl_down(wt, off);
    l1d  += __shfl_down(l1d, off);
    gld  += __shfl_down(gld, off);
    nm   += __shfl_down(nm, off);
  }
  if (lane == 0) { r0[w] = wnll; r1[w] = wt; r2[w] = l1d; r3[w] = gld; r4[w] = nm; }
  __syncthreads();
  if (tid == 0) {
    for (int x = 1; x < NW; ++x) { wnll += r0[x]; wt += r1[x]; l1d += r2[x]; gld += r3[x]; nm += r4[x]; }
    atomicAdd(&acc->wnll, wnll);
    atomicAdd(&acc->wt, wt);
    atomicAdd(&acc->l1, l1d);
    atomicAdd(&acc->gl, gld);
    atomicAdd(&acc->nm, nm);
    __threadfence();
    const int ticket = atomicAdd(&acc->counter, 1);
    if (ticket == BB - 1) {
      const double fw = atomicAdd(&acc->wnll, 0.0);
      const double fwt = atomicAdd(&acc->wt, 0.0);
      const double fl1 = atomicAdd(&acc->l1, 0.0);
      const double fgl = atomicAdd(&acc->gl, 0.0);
      int fnm = atomicAdd(&acc->nm, 0);
      if (fnm < 1) fnm = 1;
      const double loss = (double)CLS_W * (fw / fwt) +
                          ((double)L1_W * fl1 + (double)GIOU_W * fgl) / (double)fnm;
      out[0] = (float)loss;
    }
  }
}

extern "C" void kernel_launch(void* const* d_in, const int* in_sizes, int n_in,
                              void* d_out, int out_size, void* d_ws, size_t ws_size,
                              hipStream_t stream) {
  const float* logits = (const float*)d_in[0];
  const float* pboxes = (const float*)d_in[1];
  const int*   gcls   = (const int*)d_in[2];
  const float* gboxes = (const float*)d_in[3];

  char* ws = (char*)d_ws;
  Accum* acc = (Accum*)ws;                                  // 64 B, inited in cost_kernel
  float4* part = (float4*)(ws + 4096);                      // 64*8*128 float4 = 1 MB
  float* cost = (float*)(ws + 4096 + (size_t)BB * NCH * QCH * sizeof(float4));  // ~24.6 MB

  cost_kernel<<<dim3(NCH, BB), 256, 0, stream>>>(logits, pboxes, gcls, gboxes, cost, part, acc);
  jv_kernel<<<BB, NT, 0, stream>>>(logits, pboxes, gcls, gboxes, cost, part, acc, (float*)d_out);
}